// Round 9
// baseline (632.043 us; speedup 1.0000x reference)
//
#include <hip/hip_runtime.h>
#include <math.h>

constexpr float DELTA_ = 2.5f;

typedef __attribute__((ext_vector_type(8))) short bf16x8;
typedef __attribute__((ext_vector_type(8))) _Float16 f16x8;
typedef __attribute__((ext_vector_type(4))) float f32x4;

__device__ inline ushort bf16h(float x){
  union { float f; unsigned u; } v; v.f = x;
  unsigned r = v.u + 0x7fffu + ((v.u >> 16) & 1u);
  return (ushort)(r >> 16);
}
__device__ inline float bf16f(ushort h){
  union { unsigned u; float f; } v; v.u = ((unsigned)h) << 16;
  return v.f;
}

// ---------- U-weights: Wpk2[t][192][320] bf16 (col = path*64+o; path1/2 zero h-rows) ----------
__global__ __launch_bounds__(256) void k_tU(const float* __restrict__ Uw, ushort* __restrict__ Wpk2){
  int i = blockIdx.x*256 + threadIdx.x;          // i = (t*192+col)*320 + k
  if (i >= 4*192*320) return;
  int k   = i % 320;
  int col = (i/320) % 192;
  int t   = i/(320*192);
  int path = col >> 6, o = col & 63;
  float v = 0.f;
  int src = -1;
  if (k < 64){ if (path == 0) src = k; }
  else        src = k + path*256;
  if (src >= 0) v = Uw[((size_t)(t*64 + o))*832 + src];
  Wpk2[i] = bf16h(v);
}

// ---------- mix weights: Wm2[col][256] bf16 ----------
__global__ __launch_bounds__(256) void k_tMm(const float* __restrict__ mixw, ushort* __restrict__ Wm2){
  int i = blockIdx.x*256 + threadIdx.x;
  if (i >= 256*256) return;
  Wm2[i] = bf16h(mixw[i]);
}

// ---------- W_ef in B-fragment layout: Wefp[(cb*64+lane)*8+j], ch=cb*16+(lane&15), k=(lane>>4)*8+j ----------
__global__ __launch_bounds__(256) void k_tE2(const float* __restrict__ Mw, _Float16* __restrict__ Wefp){
  int i = blockIdx.x*256 + threadIdx.x;
  if (i >= 16*64*8) return;
  int j    = i & 7;
  int lane = (i >> 3) & 63;
  int cb   = i >> 9;
  int ch = cb*16 + (lane & 15);
  int k  = ((lane >> 4) & 3)*8 + j;
  Wefp[i] = (_Float16)Mw[(size_t)ch*160 + 128 + k];
}

__global__ __launch_bounds__(256) void k_hist(const int* __restrict__ dstv, int* __restrict__ cnt, int E){
  int e = blockIdx.x*256 + threadIdx.x;
  if (e < E) atomicAdd(&cnt[dstv[e]], 1);
}

__global__ __launch_bounds__(256) void k_scan1(const int* __restrict__ cnt, int* __restrict__ offs,
                                               int* __restrict__ bsum, int N){
  __shared__ int lds[256];
  int i = threadIdx.x;
  int g = blockIdx.x*256 + i;
  int v = (g < N) ? cnt[g] : 0;
  int acc = v;
  lds[i] = acc; __syncthreads();
  for (int s = 1; s < 256; s <<= 1){
    int t = (i >= s) ? lds[i - s] : 0;
    __syncthreads();
    acc += t; lds[i] = acc;
    __syncthreads();
  }
  if (g < N) offs[g] = acc - v;
  if (i == 255) bsum[blockIdx.x] = acc;
}

__global__ __launch_bounds__(256) void k_scan2(int* __restrict__ bsum, int NB){
  __shared__ int lds[256];
  int i = threadIdx.x;
  int v = (i < NB) ? bsum[i] : 0;
  int acc = v;
  lds[i] = acc; __syncthreads();
  for (int s = 1; s < 256; s <<= 1){
    int t = (i >= s) ? lds[i - s] : 0;
    __syncthreads();
    acc += t; lds[i] = acc;
    __syncthreads();
  }
  if (i < NB) bsum[i] = acc - v;
}

__global__ __launch_bounds__(256) void k_scan3(int* __restrict__ offs, const int* __restrict__ bsum, int N, int E){
  int g = blockIdx.x*256 + threadIdx.x;
  if (g < N) offs[g] += bsum[blockIdx.x];
  if (g == 0) offs[N] = E;
}

__global__ __launch_bounds__(256) void k_fill(const int* __restrict__ dstv, const int* __restrict__ offs,
                                              int* __restrict__ cur, int* __restrict__ elist, int E){
  int e = blockIdx.x*256 + threadIdx.x;
  if (e < E){
    int d = dstv[e];
    elist[offs[d] + atomicAdd(&cur[d], 1)] = e;
  }
}

// ---------- permute srcv + edge features (f16) into CSR order ----------
__global__ __launch_bounds__(256) void k_perm(const int* __restrict__ elist, const int* __restrict__ srcv,
                                              const float* __restrict__ efeat,
                                              int* __restrict__ esrc, _Float16* __restrict__ efh, int E){
  int g = blockIdx.x*256 + threadIdx.x;
  int pos = g >> 3;
  int q   = g & 7;
  if (pos >= E) return;
  int e = elist[pos];
  if (q == 0) esrc[pos] = srcv[e];
  float4 v = *(const float4*)(efeat + (size_t)e*32 + q*4);
  union { ushort4 u; _Float16 h[4]; } cv;
  cv.h[0] = (_Float16)v.x; cv.h[1] = (_Float16)v.y;
  cv.h[2] = (_Float16)v.z; cv.h[3] = (_Float16)v.w;
  *(ushort4*)(efh + (size_t)pos*32 + q*4) = cv.u;
}

// ---------- A_h = f16(W_src*h), B = W_dst*h + M_b; also writes X2 h-part ----------
__global__ __launch_bounds__(256) void k_ab(const float* __restrict__ nf, const float* __restrict__ Mw,
                                            const float* __restrict__ Mb,
                                            _Float16* __restrict__ A_h, float* __restrict__ B,
                                            ushort* __restrict__ X2, int N){
  int c = threadIdx.x;
  int t = __builtin_amdgcn_readfirstlane(threadIdx.x >> 6);
  float ws[64], wd[64];
  const float* row = Mw + (size_t)c*160;
#pragma unroll
  for (int k = 0; k < 64; k += 4){
    float4 a = *(const float4*)(row + k);
    float4 b = *(const float4*)(row + 64 + k);
    ws[k]=a.x; ws[k+1]=a.y; ws[k+2]=a.z; ws[k+3]=a.w;
    wd[k]=b.x; wd[k+1]=b.y; wd[k+2]=b.z; wd[k+3]=b.w;
  }
  float bias = Mb[c];
  for (int n = blockIdx.x; n < N; n += gridDim.x){
    const float* h = nf + (size_t)n*256 + t*64;
    float sa = 0.f, sb = 0.f;
#pragma unroll
    for (int k = 0; k < 64; k += 4){
      float4 h4 = *(const float4*)(h + k);
      sa = fmaf(ws[k], h4.x, sa);  sb = fmaf(wd[k], h4.x, sb);
      sa = fmaf(ws[k+1], h4.y, sa); sb = fmaf(wd[k+1], h4.y, sb);
      sa = fmaf(ws[k+2], h4.z, sa); sb = fmaf(wd[k+2], h4.z, sb);
      sa = fmaf(ws[k+3], h4.w, sa); sb = fmaf(wd[k+3], h4.w, sb);
    }
    A_h[(size_t)n*256 + c] = (_Float16)sa;
    B[(size_t)n*256 + c] = sb + bias;
    // X2 h-part for channel c (nf row is L1-hot)
    float v = nf[(size_t)n*256 + c];
    ushort hi = bf16h(v);
    int d = c & 63, j = d >> 3, pp = d & 7;
    size_t base = (((size_t)n*4 + t)*40 + j)*16;
    X2[base + pp]     = hi;
    X2[base + 8 + pp] = bf16h(v - bf16f(hi));
  }
}

// ---------- aggregation: MFMA eproj + scalar gather/aggregate ----------
// block = node (256 thr, 4 waves); wave wv owns channels [wv*64, wv*64+64) as 4 col-blocks.
// Per 16-edge CSR chunk: A-frag = 16 efh rows (f16), eproj = mfma(A, Wef_frag).
// b0 commutes out: m' = eproj + A_src; S = cnt*b0 + Σm'; SS = cnt*b0² + 2b0Σm' + Σm'²;
// max m = b0 + max m'.
__global__ __launch_bounds__(256) void k_agg(const int* __restrict__ offs, const int* __restrict__ esrc,
                                             const _Float16* __restrict__ efh,
                                             const _Float16* __restrict__ A_h, const float* __restrict__ B,
                                             const _Float16* __restrict__ Wefp,
                                             ushort* __restrict__ X2, float* __restrict__ sc, int N, int E){
  int n = blockIdx.x;
  if (n >= N) return;
  int tid = threadIdx.x;
  int lane = tid & 63, wv = tid >> 6;
  int li = lane & 15, kq = lane >> 4;

  int o0 = offs[n], o1 = offs[n+1];
  int cnt = o1 - o0;

  f16x8 bf[4];
#pragma unroll
  for (int cbl = 0; cbl < 4; ++cbl)
    bf[cbl] = *(const f16x8*)(Wefp + ((size_t)(wv*4 + cbl)*64 + lane)*8);

  float b0[4];
#pragma unroll
  for (int cbl = 0; cbl < 4; ++cbl)
    b0[cbl] = B[(size_t)n*256 + wv*64 + cbl*16 + li];

  float s[4]  = {0.f,0.f,0.f,0.f};
  float ss[4] = {0.f,0.f,0.f,0.f};
  float mx[4], mn[4];
#pragma unroll
  for (int cbl = 0; cbl < 4; ++cbl){
    mx[cbl] = -__builtin_huge_valf();
    mn[cbl] =  __builtin_huge_valf();
  }

  for (int p = o0; p < o1; p += 16){
    int posa = p + li; if (posa > E - 1) posa = E - 1;
    f16x8 af = *(const f16x8*)(efh + (size_t)posa*32 + kq*8);
    f32x4 ep0 = __builtin_amdgcn_mfma_f32_16x16x32_f16(af, bf[0], (f32x4)0.f, 0, 0, 0);
    f32x4 ep1 = __builtin_amdgcn_mfma_f32_16x16x32_f16(af, bf[1], (f32x4)0.f, 0, 0, 0);
    f32x4 ep2 = __builtin_amdgcn_mfma_f32_16x16x32_f16(af, bf[2], (f32x4)0.f, 0, 0, 0);
    f32x4 ep3 = __builtin_amdgcn_mfma_f32_16x16x32_f16(af, bf[3], (f32x4)0.f, 0, 0, 0);
#pragma unroll
    for (int r = 0; r < 4; ++r){
      int pr = p + kq*4 + r;
      if (pr < o1){
        int srcn = esrc[pr];
        const _Float16* ap = A_h + (size_t)srcn*256 + wv*64 + li;
        float a0 = (float)ap[0];
        float a1 = (float)ap[16];
        float a2 = (float)ap[32];
        float a3 = (float)ap[48];
        float m0 = ep0[r] + a0;
        float m1 = ep1[r] + a1;
        float m2 = ep2[r] + a2;
        float m3 = ep3[r] + a3;
        s[0] += m0; ss[0] = fmaf(m0, m0, ss[0]); mx[0] = fmaxf(mx[0], m0); mn[0] = fminf(mn[0], m0);
        s[1] += m1; ss[1] = fmaf(m1, m1, ss[1]); mx[1] = fmaxf(mx[1], m1); mn[1] = fminf(mn[1], m1);
        s[2] += m2; ss[2] = fmaf(m2, m2, ss[2]); mx[2] = fmaxf(mx[2], m2); mn[2] = fminf(mn[2], m2);
        s[3] += m3; ss[3] = fmaf(m3, m3, ss[3]); mx[3] = fmaxf(mx[3], m3); mn[3] = fminf(mn[3], m3);
      }
    }
  }

  // reduce across the 4 row-groups (lanes l, l^16, l^32, l^48 share a channel)
#pragma unroll
  for (int cbl = 0; cbl < 4; ++cbl){
    s[cbl]  += __shfl_xor(s[cbl], 16);  s[cbl]  += __shfl_xor(s[cbl], 32);
    ss[cbl] += __shfl_xor(ss[cbl], 16); ss[cbl] += __shfl_xor(ss[cbl], 32);
    mx[cbl] = fmaxf(mx[cbl], __shfl_xor(mx[cbl], 16));
    mx[cbl] = fmaxf(mx[cbl], __shfl_xor(mx[cbl], 32));
    mn[cbl] = fminf(mn[cbl], __shfl_xor(mn[cbl], 16));
    mn[cbl] = fminf(mn[cbl], __shfl_xor(mn[cbl], 32));
  }

  if (lane < 16){
    float deg  = (float)cnt;
    float degc = fmaxf(deg, 1.f);
    float inv  = 1.f / degc;
#pragma unroll
    for (int cbl = 0; cbl < 4; ++cbl){
      float b = b0[cbl];
      float S  = fmaf(deg, b, s[cbl]);
      float SS = fmaf(deg, b*b, fmaf(2.f*b, s[cbl], ss[cbl]));
      float mean = S * inv;
      float var  = fmaxf(SS * inv - mean*mean, 0.f);
      float sd   = sqrtf(var + 1e-30f);
      float MX = (cnt > 0) ? (b + mx[cbl]) : 0.f;
      float MN = (cnt > 0) ? (b + mn[cbl]) : 0.f;
      int d = cbl*16 + li;                      // within tower wv
#define PUTX(SLOT, VAL) { int kk = 64 + (SLOT)*64 + d; int jj = kk >> 3, pp = kk & 7;     \
      size_t base = (((size_t)n*4 + wv)*40 + jj)*16;                                       \
      ushort hi2 = bf16h(VAL);                                                             \
      X2[base + pp] = hi2; X2[base + 8 + pp] = bf16h((VAL) - bf16f(hi2)); }
      PUTX(0, mean) PUTX(1, MX) PUTX(2, MN) PUTX(3, sd)
#undef PUTX
    }
  }
  if (tid == 0){
    float deg = (float)cnt;
    float logd = logf(deg + 1.f);
    sc[(size_t)n*2]     = logd * (1.f / DELTA_);
    sc[(size_t)n*2 + 1] = (cnt > 0) ? (DELTA_ / fmaxf(logd, 1e-12f)) : 0.f;
  }
}

// ---------- U GEMM: LDS-free MFMA + fused BN partial stats ----------
// grid (NBLK, 4 towers), 256 thr = 4 waves; wave w owns cols [w*48, w*48+48).
__global__ __launch_bounds__(256) void k_u(const ushort* __restrict__ X2, const ushort* __restrict__ Wpk2,
                                           const float* __restrict__ sc, const float* __restrict__ Ub,
                                           float* __restrict__ uout, float* __restrict__ part,
                                           int Nn, int NBLK){
  __shared__ float su[64][68];
  __shared__ float pbn[2][4][64];
  int tid = threadIdx.x;
  int t   = blockIdx.y;
  int nbase = blockIdx.x*64;
  int lane = tid & 63, wv = tid >> 6;
  int li = lane & 15, kc = lane >> 4;
  int cbase = wv*48;

  f32x4 acc[4][3];
#pragma unroll
  for (int ri = 0; ri < 4; ++ri)
#pragma unroll
    for (int ci = 0; ci < 3; ++ci) acc[ri][ci] = (f32x4)0.f;

  const ushort* wb = Wpk2 + (size_t)t*192*320;

#pragma unroll 2
  for (int kt = 0; kt < 10; ++kt){
    bf16x8 ah[4], al[4], bh[3];
#pragma unroll
    for (int ri = 0; ri < 4; ++ri){
      int row = nbase + ri*16 + li;
      if (row >= Nn) row = Nn - 1;
      const ushort* ap = X2 + (((size_t)row*4 + t)*40 + kt*4 + kc)*16;
      ah[ri] = *(const bf16x8*)(ap);
      al[ri] = *(const bf16x8*)(ap + 8);
    }
#pragma unroll
    for (int ci = 0; ci < 3; ++ci){
      int col = cbase + ci*16 + li;
      bh[ci] = *(const bf16x8*)(wb + (size_t)col*320 + kt*32 + kc*8);
    }
#pragma unroll
    for (int ci = 0; ci < 3; ++ci)
#pragma unroll
      for (int ri = 0; ri < 4; ++ri){
        acc[ri][ci] = __builtin_amdgcn_mfma_f32_16x16x32_bf16(ah[ri], bh[ci], acc[ri][ci], 0, 0, 0);
        acc[ri][ci] = __builtin_amdgcn_mfma_f32_16x16x32_bf16(al[ri], bh[ci], acc[ri][ci], 0, 0, 0);
      }
  }

  // epilogue: u = y1 + amp*y2 + att*y3 (phased, col-disjoint per phase)
#define Y1_STORE(CI, OB) { _Pragma("unroll") for (int ri = 0; ri < 4; ++ri)               \
    { _Pragma("unroll") for (int r = 0; r < 4; ++r)                                        \
      su[ri*16 + kc*4 + r][(OB) + li] = acc[ri][CI][r]; } }
#define Y_ADD(CI, OB, SCOFF) { _Pragma("unroll") for (int ri = 0; ri < 4; ++ri)           \
    { _Pragma("unroll") for (int r = 0; r < 4; ++r){                                       \
      int node = ri*16 + kc*4 + r;                                                        \
      int gn = nbase + node; int gnc = (gn < Nn) ? gn : (Nn - 1);                          \
      float scl = sc[(size_t)gnc*2 + (SCOFF)];                                            \
      su[node][(OB) + li] += scl * acc[ri][CI][r]; } } }

  if (wv == 0){ Y1_STORE(0, 0)  Y1_STORE(1, 16) Y1_STORE(2, 32) }
  else if (wv == 1){ Y1_STORE(0, 48) }
  __syncthreads();
  if (wv == 1){ Y_ADD(1, 0, 0)  Y_ADD(2, 16, 0) }
  else if (wv == 2){ Y_ADD(0, 32, 0) Y_ADD(1, 48, 0) }
  __syncthreads();
  if (wv == 2){ Y_ADD(2, 0, 1) }
  else if (wv == 3){ Y_ADD(0, 16, 1) Y_ADD(1, 32, 1) Y_ADD(2, 48, 1) }
  __syncthreads();
#undef Y1_STORE
#undef Y_ADD

  for (int idx = tid; idx < 64*16; idx += 256){
    int n = idx >> 4, o4 = (idx & 15)*4;
    int gn = nbase + n;
    if (gn < Nn){
      float4 v = *(float4*)(&su[n][o4]);
      const float* ubp = Ub + t*64 + o4;
      v.x += ubp[0]; v.y += ubp[1]; v.z += ubp[2]; v.w += ubp[3];
      *(float4*)(&uout[(size_t)gn*256 + t*64 + o4]) = v;
    }
  }

  // fused BN partial stats over this block's valid nodes (deterministic)
  {
    int cl = tid & 63, grp = tid >> 6;
    float ubv = Ub[t*64 + cl];
    float ps = 0.f, pss = 0.f;
#pragma unroll
    for (int q = 0; q < 16; ++q){
      int nn = grp*16 + q;
      if (nbase + nn < Nn){
        float v = su[nn][cl] + ubv;
        ps += v;
        pss = fmaf(v, v, pss);
      }
    }
    pbn[0][grp][cl] = ps;
    pbn[1][grp][cl] = pss;
  }
  __syncthreads();
  if (tid < 128){
    int which = tid >> 6, cl = tid & 63;
    float v = pbn[which][0][cl] + pbn[which][1][cl] + pbn[which][2][cl] + pbn[which][3][cl];
    part[((size_t)t*NBLK + blockIdx.x)*128 + which*64 + cl] = v;
  }
}

// ---------- BN finalize (reduce per-block partials) ----------
__global__ __launch_bounds__(256) void k_bnfin(const float* __restrict__ part, const float* __restrict__ gam,
                                               const float* __restrict__ bet, float* __restrict__ bnsc,
                                               int N, int NBLK){
  int c = threadIdx.x;
  int t = c >> 6, cl = c & 63;
  float s = 0.f, ss = 0.f;
  for (int b = 0; b < NBLK; ++b){
    const float* pp = part + ((size_t)t*NBLK + b)*128;
    s  += pp[cl];
    ss += pp[64 + cl];
  }
  float invN = 1.f / (float)N;
  float mu  = s * invN;
  float ex2 = ss * invN;
  float var = fmaxf(ex2 - mu*mu, 0.f);
  float inv = 1.f / sqrtf(var + 1e-5f);
  float scale = gam[c] * inv;
  bnsc[c]       = scale;
  bnsc[256 + c] = bet[c] - mu*scale;
}

// ---------- X2m = bf16 hi/lo of (u*s + b), fragment-native [n][32][hi8|lo8] ----------
__global__ __launch_bounds__(256) void k_xm(const float* __restrict__ u, const float* __restrict__ bnsc,
                                            ushort* __restrict__ X2m, int N){
  for (long i = blockIdx.x*256 + threadIdx.x; i < (long)N*256; i += (long)gridDim.x*256){
    int n = (int)(i >> 8), c = (int)(i & 255);
    float v = fmaf(u[i], bnsc[c], bnsc[256 + c]);
    int j = c >> 3, pos = c & 7;
    size_t base = ((size_t)n*32 + j)*16;
    ushort hi = bf16h(v);
    X2m[base + pos]     = hi;
    X2m[base + 8 + pos] = bf16h(v - bf16f(hi));
  }
}

// ---------- mix GEMM: LDS-free MFMA + fused leaky/residual/relu ----------
__global__ __launch_bounds__(256) void k_mix(const ushort* __restrict__ X2m, const ushort* __restrict__ Wm2,
                                             const float* __restrict__ mixb, const float* __restrict__ nf,
                                             float* __restrict__ outp, int Nn){
  int tid = threadIdx.x;
  int nbase = blockIdx.x*64;
  int lane = tid & 63, wv = tid >> 6;
  int li = lane & 15, kc = lane >> 4;

  f32x4 acc[4][4];
#pragma unroll
  for (int ri = 0; ri < 4; ++ri)
#pragma unroll
    for (int ci = 0; ci < 4; ++ci) acc[ri][ci] = (f32x4)0.f;

#pragma unroll 2
  for (int kt = 0; kt < 8; ++kt){
    bf16x8 ah[4], al[4], bh[4];
#pragma unroll
    for (int ri = 0; ri < 4; ++ri){
      int row = nbase + ri*16 + li;
      if (row >= Nn) row = Nn - 1;
      const ushort* ap = X2m + (((size_t)row*32 + kt*4 + kc))*16;
      ah[ri] = *(const bf16x8*)(ap);
      al[ri] = *(const bf16x8*)(ap + 8);
    }
#pragma unroll
    for (int ci = 0; ci < 4; ++ci){
      int col = wv*64 + ci*16 + li;
      bh[ci] = *(const bf16x8*)(Wm2 + (size_t)col*256 + kt*32 + kc*8);
    }
#pragma unroll
    for (int ci = 0; ci < 4; ++ci)
#pragma unroll
      for (int ri = 0; ri < 4; ++ri){
        acc[ri][ci] = __builtin_amdgcn_mfma_f32_16x16x32_bf16(ah[ri], bh[ci], acc[ri][ci], 0, 0, 0);
        acc[ri][ci] = __builtin_amdgcn_mfma_f32_16x16x32_bf16(al[ri], bh[ci], acc[ri][ci], 0, 0, 0);
      }
  }

#pragma unroll
  for (int ri = 0; ri < 4; ++ri){
#pragma unroll
    for (int r = 0; r < 4; ++r){
      int node = ri*16 + kc*4 + r;
      int gn = nbase + node;
      if (gn < Nn){
#pragma unroll
        for (int ci = 0; ci < 4; ++ci){
          int col = wv*64 + ci*16 + li;
          float m = acc[ri][ci][r] + mixb[col];
          m = (m > 0.f) ? m : 0.01f*m;
          float o = m + nf[(size_t)gn*256 + col];
          outp[(size_t)gn*256 + col] = fmaxf(o, 0.f);
        }
      }
    }
  }
}

// ---------- host launcher ----------
extern "C" void kernel_launch(void* const* d_in, const int* in_sizes, int n_in,
                              void* d_out, int out_size, void* d_ws, size_t ws_size,
                              hipStream_t stream){
  const float* nf   = (const float*)d_in[0];
  const float* ef   = (const float*)d_in[1];
  const int*   srcv = (const int*)  d_in[2];
  const int*   dstv = (const int*)  d_in[3];
  const float* Mw   = (const float*)d_in[4];
  const float* Mb   = (const float*)d_in[5];
  const float* Uw   = (const float*)d_in[6];
  const float* Ub   = (const float*)d_in[7];
  const float* gam  = (const float*)d_in[8];
  const float* bet  = (const float*)d_in[9];
  const float* mixw = (const float*)d_in[10];
  const float* mixb = (const float*)d_in[11];
  int N = in_sizes[0] / 256;
  int E = in_sizes[2];
  float* out = (float*)d_out;
  int NBLK = (N + 63)/64;

  char* wp = (char*)d_ws;
  auto alloc = [&](size_t bytes){
    char* p = wp;
    wp += (bytes + 1023) & ~(size_t)1023;
    return (void*)p;
  };
  int*      cnt   = (int*)     alloc((size_t)N*4);
  int*      offs  = (int*)     alloc((size_t)(N+1)*4);
  int*      cur   = (int*)     alloc((size_t)N*4);
  int*      bsum  = (int*)     alloc(256*4);
  int*      elist = (int*)     alloc((size_t)E*4);
  int*      esrc  = (int*)     alloc((size_t)E*4);
  // efh is dead after k_agg; X2m (written by k_xm) aliases it.
  size_t ealias   = (size_t)E*32*2;
  size_t malias   = (size_t)N*512*2;
  char*     shbuf = (char*)    alloc(ealias > malias ? ealias : malias);
  _Float16* efh   = (_Float16*)shbuf;
  ushort*   X2m   = (ushort*)  shbuf;
  _Float16* A_h   = (_Float16*)alloc((size_t)N*256*2);
  float*    B     = (float*)   alloc((size_t)N*256*4);
  float*    sc    = (float*)   alloc((size_t)N*2*4);
  float*    part  = (float*)   alloc((size_t)4*NBLK*128*4);
  float*    bnsc  = (float*)   alloc(512*4);
  ushort*   X2    = (ushort*)  alloc((size_t)N*4*40*16*2);
  ushort*   Wpk2  = (ushort*)  alloc((size_t)4*192*320*2);
  ushort*   Wm2   = (ushort*)  alloc((size_t)256*256*2);
  _Float16* Wefp  = (_Float16*)alloc((size_t)16*64*8*2);

  hipMemsetAsync(cnt,  0, (size_t)N*4,  stream);
  hipMemsetAsync(cur,  0, (size_t)N*4,  stream);

  k_tU  <<<(4*192*320 + 255)/256, 256, 0, stream>>>(Uw, Wpk2);
  k_tMm <<<(256*256 + 255)/256, 256, 0, stream>>>(mixw, Wm2);
  k_tE2 <<<(16*64*8 + 255)/256, 256, 0, stream>>>(Mw, Wefp);
  k_hist<<<(E + 255)/256, 256, 0, stream>>>(dstv, cnt, E);
  k_ab  <<<2048, 256, 0, stream>>>(nf, Mw, Mb, A_h, B, X2, N);

  int NB = (N + 255)/256;
  k_scan1<<<NB, 256, 0, stream>>>(cnt, offs, bsum, N);
  k_scan2<<<1, 256, 0, stream>>>(bsum, NB);
  k_scan3<<<NB, 256, 0, stream>>>(offs, bsum, N, E);
  k_fill <<<(E + 255)/256, 256, 0, stream>>>(dstv, offs, cur, elist, E);
  k_perm <<<(E*8 + 255)/256, 256, 0, stream>>>(elist, srcv, ef, esrc, efh, E);

  k_agg<<<N, 256, 0, stream>>>(offs, esrc, efh, A_h, B, Wefp, X2, sc, N, E);

  dim3 ugrid(NBLK, 4);
  k_u<<<ugrid, 256, 0, stream>>>(X2, Wpk2, sc, Ub, out, part, N, NBLK);

  k_bnfin<<<1, 256, 0, stream>>>(part, gam, bet, bnsc, N, NBLK);
  k_xm   <<<2048, 256, 0, stream>>>(out, bnsc, X2m, N);
  k_mix  <<<NBLK, 256, 0, stream>>>(X2m, Wm2, mixb, nf, out, N);
}